// Round 3
// baseline (146.646 us; speedup 1.0000x reference)
//
#include <hip/hip_runtime.h>

#define ED 256
#define NHEAD 8
#define NPTS 8
#define DHEAD 32
#define QPB 8   // queries per block (2 groups of 4 waves x 1 query)

// ---------------------------------------------------------------------------
// Kernel A: per-batch precompute. query is [bs,1,ED] broadcast over all query
// positions, so relu(q@W_off+b) [128] and softmax(relu(q@W_attn+b)) [64]
// depend only on batch. ws layout per batch: off[128] then aw[64] (192 floats).
// ---------------------------------------------------------------------------
__global__ __launch_bounds__(256) void precompute_kernel(
    const float* __restrict__ query,
    const float* __restrict__ W_off, const float* __restrict__ b_off,
    const float* __restrict__ W_attn, const float* __restrict__ b_attn,
    float* __restrict__ ws)
{
    const int b = blockIdx.x;
    const int t = threadIdx.x;
    __shared__ float sq[ED];
    __shared__ float sattn[NHEAD * NPTS];

    sq[t] = query[b * ED + t];
    __syncthreads();

    if (t < 128) {
        float a0 = 0.f, a1 = 0.f, a2 = 0.f, a3 = 0.f;
        #pragma unroll 4
        for (int k = 0; k < ED; k += 4) {
            a0 = fmaf(sq[k + 0], W_off[(k + 0) * 128 + t], a0);
            a1 = fmaf(sq[k + 1], W_off[(k + 1) * 128 + t], a1);
            a2 = fmaf(sq[k + 2], W_off[(k + 2) * 128 + t], a2);
            a3 = fmaf(sq[k + 3], W_off[(k + 3) * 128 + t], a3);
        }
        ws[b * 192 + t] = fmaxf(b_off[t] + ((a0 + a1) + (a2 + a3)), 0.0f);
    } else if (t < 192) {
        const int j = t - 128;
        float a0 = 0.f, a1 = 0.f, a2 = 0.f, a3 = 0.f;
        #pragma unroll 4
        for (int k = 0; k < ED; k += 4) {
            a0 = fmaf(sq[k + 0], W_attn[(k + 0) * 64 + j], a0);
            a1 = fmaf(sq[k + 1], W_attn[(k + 1) * 64 + j], a1);
            a2 = fmaf(sq[k + 2], W_attn[(k + 2) * 64 + j], a2);
            a3 = fmaf(sq[k + 3], W_attn[(k + 3) * 64 + j], a3);
        }
        sattn[j] = fmaxf(b_attn[j] + ((a0 + a1) + (a2 + a3)), 0.0f);
    }
    __syncthreads();

    if (t >= 128 && t < 192) {
        const int j = t - 128;
        const int hh = j >> 3;
        float m = -1e30f;
        #pragma unroll
        for (int p = 0; p < NPTS; ++p) m = fmaxf(m, sattn[hh * NPTS + p]);
        float s = 0.0f;
        #pragma unroll
        for (int p = 0; p < NPTS; ++p) s += expf(sattn[hh * NPTS + p] - m);
        ws[b * 192 + 128 + j] = expf(sattn[j] - m) / s;
    }
}

// ---------------------------------------------------------------------------
// Kernel B v3: 8 queries per block. Phase 1 computes all 8x64 (q,h,p)
// coordinate tuples (2 per thread) into LDS [q][p][h]{int4 idx, float4 w}.
// Phase 2: wave qL processes query gq*4+qL with an explicit 2-point-deep
// software pipeline: issue point p+1's LDS reads + 4 corner dwordx4 loads
// while FMA-consuming point p (keeps ~8 global loads in flight per wave,
// VGPR 36 was too lean in v2). Phase 3: wave-local residual + LayerNorm.
// blockIdx % bs pins batch b to XCD b (bs==8): its 4MB feat map stays in one
// XCD's L2 (FETCH_SIZE ~= one cold read of feat confirms reuse hits L2).
// ---------------------------------------------------------------------------
__global__ __launch_bounds__(256) void deform_attn_kernel(
    const float* __restrict__ feat,     // [bs, nq, NHEAD, DHEAD]
    const float* __restrict__ ref2d,    // [bs, nq, 1, 2]
    const float* __restrict__ query,    // [bs, 1, ED]
    const float* __restrict__ ln_g, const float* __restrict__ ln_b,
    const float* __restrict__ ws,       // [bs, 192]
    const int* __restrict__ Hp, const int* __restrict__ Wp,
    float* __restrict__ out,            // [bs, nq, ED]
    int nq, int bs)
{
    const int blk = blockIdx.x;
    const int b = blk % bs;                    // XCD swizzle
    const int qbase = (blk / bs) * QPB;
    const int t = threadIdx.x;

    __shared__ float s_off[128];
    __shared__ float s_aw[64];
    __shared__ float s_ref[QPB * 2];
    __shared__ __align__(16) float s_c[QPB * 64 * 8];  // [q][p][h] x {idx4, w4}

    if (t < 128)      s_off[t] = ws[b * 192 + t];
    else if (t < 192) s_aw[t - 128] = ws[b * 192 + t];
    else if (t < 192 + QPB * 2) {
        const int i = t - 192;                 // i = qL*2 + j
        s_ref[i] = ref2d[(b * nq + qbase + (i >> 1)) * 2 + (i & 1)];
    }
    const int H = Hp[0];
    const int W = Wp[0];
    __syncthreads();

    // ---- Phase 1: 8*64 tuples, 2 per thread ----
    #pragma unroll
    for (int u = t; u < QPB * 64; u += 256) {
        const int qL = u >> 6;
        const int hp = u & 63;                 // h*8 + p
        const int p  = hp & 7;
        const int h  = hp >> 3;

        const float x = s_ref[qL * 2 + 0] * (float)W - 0.5f + s_off[hp * 2 + 0];
        const float y = s_ref[qL * 2 + 1] * (float)H - 0.5f + s_off[hp * 2 + 1];
        const float aw = s_aw[hp];

        const float xf = floorf(x);
        const float yf = floorf(y);
        const int ix = (int)xf;
        const int iy = (int)yf;
        const float wx = x - xf;
        const float wy = y - yf;

        const bool vx0 = (ix >= 0) && (ix < W);
        const bool vx1 = (ix + 1 >= 0) && (ix + 1 < W);
        const bool vy0 = (iy >= 0) && (iy < H);
        const bool vy1 = (iy + 1 >= 0) && (iy + 1 < H);
        const int cx0 = min(max(ix, 0), W - 1);
        const int cx1 = min(max(ix + 1, 0), W - 1);
        const int cy0 = min(max(iy, 0), H - 1);
        const int cy1 = min(max(iy + 1, 0), H - 1);

        const int r0 = cy0 * W;
        const int r1 = cy1 * W;
        int4 idx;
        idx.x = r0 + cx0;
        idx.y = r0 + cx1;
        idx.z = r1 + cx0;
        idx.w = r1 + cx1;

        const float awx = aw * wx, awix = aw - awx;     // aw*(1-wx)
        float4 wt;
        wt.x = (vx0 && vy0) ? awix * (1.0f - wy) : 0.0f;
        wt.y = (vx1 && vy0) ? awx  * (1.0f - wy) : 0.0f;
        wt.z = (vx0 && vy1) ? awix * wy          : 0.0f;
        wt.w = (vx1 && vy1) ? awx  * wy          : 0.0f;

        const int e = (qL * 64 + p * 8 + h) * 8;        // [q][p][h], 8 dwords
        *(int4*)  (&s_c[e])     = idx;
        *(float4*)(&s_c[e + 4]) = wt;
    }
    __syncthreads();

    // ---- Phase 2: pipelined gather. lane within wave; h = lane>>3, c4 = lane&7 ----
    const int qL   = t >> 6;
    const int lane = t & 63;
    const int h    = lane >> 3;
    const int c4   = lane & 7;

    const float* fb = feat + (size_t)b * nq * ED + h * DHEAD + c4 * 4;
    const float4 qv = *(const float4*)(query + b * ED + lane * 4);
    const float4 g  = *(const float4*)(ln_g + lane * 4);
    const float4 be = *(const float4*)(ln_b + lane * 4);

    #pragma unroll
    for (int gq = 0; gq < QPB / 4; ++gq) {
        const int qloc = gq * 4 + qL;
        const int q = qbase + qloc;
        const int cb = qloc * 512;             // base into s_c for this query

        float ax = 0.f, ay = 0.f, az = 0.f, aw4 = 0.f;

        // prologue: point 0
        int4   idxA = *(const int4*)  (&s_c[cb + h * 8]);
        float4 wtA  = *(const float4*)(&s_c[cb + h * 8 + 4]);
        float4 v0 = *(const float4*)(fb + (size_t)idxA.x * ED);
        float4 v1 = *(const float4*)(fb + (size_t)idxA.y * ED);
        float4 v2 = *(const float4*)(fb + (size_t)idxA.z * ED);
        float4 v3 = *(const float4*)(fb + (size_t)idxA.w * ED);

        #pragma unroll
        for (int p = 0; p < NPTS; ++p) {
            int4 idxB; float4 wtB;
            float4 u0, u1, u2, u3;
            if (p < NPTS - 1) {
                const int e = cb + (p + 1) * 64 + h * 8;
                idxB = *(const int4*)  (&s_c[e]);
                wtB  = *(const float4*)(&s_c[e + 4]);
                u0 = *(const float4*)(fb + (size_t)idxB.x * ED);
                u1 = *(const float4*)(fb + (size_t)idxB.y * ED);
                u2 = *(const float4*)(fb + (size_t)idxB.z * ED);
                u3 = *(const float4*)(fb + (size_t)idxB.w * ED);
            }
            ax = fmaf(wtA.x, v0.x, ax); ay = fmaf(wtA.x, v0.y, ay);
            az = fmaf(wtA.x, v0.z, az); aw4 = fmaf(wtA.x, v0.w, aw4);
            ax = fmaf(wtA.y, v1.x, ax); ay = fmaf(wtA.y, v1.y, ay);
            az = fmaf(wtA.y, v1.z, az); aw4 = fmaf(wtA.y, v1.w, aw4);
            ax = fmaf(wtA.z, v2.x, ax); ay = fmaf(wtA.z, v2.y, ay);
            az = fmaf(wtA.z, v2.z, az); aw4 = fmaf(wtA.z, v2.w, aw4);
            ax = fmaf(wtA.w, v3.x, ax); ay = fmaf(wtA.w, v3.y, ay);
            az = fmaf(wtA.w, v3.z, az); aw4 = fmaf(wtA.w, v3.w, aw4);
            if (p < NPTS - 1) {
                idxA = idxB; wtA = wtB;
                v0 = u0; v1 = u1; v2 = u2; v3 = u3;
            }
        }

        // ---- Phase 3: residual + wave-local LayerNorm ----
        const float r0 = ax + qv.x;
        const float r1 = ay + qv.y;
        const float r2 = az + qv.z;
        const float r3 = aw4 + qv.w;

        float s  = (r0 + r1) + (r2 + r3);
        float ss = fmaf(r0, r0, fmaf(r1, r1, fmaf(r2, r2, r3 * r3)));
        #pragma unroll
        for (int m = 1; m < 64; m <<= 1) {
            s  += __shfl_xor(s, m, 64);
            ss += __shfl_xor(ss, m, 64);
        }
        const float mean = s * (1.0f / ED);
        const float var  = ss * (1.0f / ED) - mean * mean;
        const float inv  = rsqrtf(var + 1e-5f);

        float4 o;
        o.x = (r0 - mean) * inv * g.x + be.x;
        o.y = (r1 - mean) * inv * g.y + be.y;
        o.z = (r2 - mean) * inv * g.z + be.z;
        o.w = (r3 - mean) * inv * g.w + be.w;
        *(float4*)(out + ((size_t)b * nq + q) * ED + lane * 4) = o;
    }
}

extern "C" void kernel_launch(void* const* d_in, const int* in_sizes, int n_in,
                              void* d_out, int out_size, void* d_ws, size_t ws_size,
                              hipStream_t stream)
{
    const float* query  = (const float*)d_in[0];
    const float* feat   = (const float*)d_in[1];
    const float* ref2d  = (const float*)d_in[2];
    const float* W_off  = (const float*)d_in[3];
    const float* b_off  = (const float*)d_in[4];
    const float* W_attn = (const float*)d_in[5];
    const float* b_attn = (const float*)d_in[6];
    const float* ln_g   = (const float*)d_in[7];
    const float* ln_b   = (const float*)d_in[8];
    const int*   Hp     = (const int*)d_in[9];
    const int*   Wp     = (const int*)d_in[10];
    float* out = (float*)d_out;
    float* ws  = (float*)d_ws;

    const int bs = in_sizes[0] / ED;            // 8
    const int nq = in_sizes[2] / (bs * 2);      // h*w = 4096

    precompute_kernel<<<bs, 256, 0, stream>>>(query, W_off, b_off, W_attn, b_attn, ws);
    deform_attn_kernel<<<bs * nq / QPB, 256, 0, stream>>>(feat, ref2d, query, ln_g, ln_b,
                                                          ws, Hp, Wp, out, nq, bs);
}

// Round 4
// 145.023 us; speedup vs baseline: 1.0112x; 1.0112x over previous
//
#include <hip/hip_runtime.h>

#define ED 256
#define NHEAD 8
#define NPTS 8
#define DHEAD 32
#define QPB 8   // queries per block (2 passes of 4 waves x 1 query)

// ---------------------------------------------------------------------------
// Kernel A v2: per-batch precompute with K-split. query is [bs,1,ED]
// broadcast, so off[128] and softmax(aw)[64] depend only on batch.
// off: 128 cols x 2-way K-split; attn: 64 cols x 4-way K-split; LDS-reduce.
// ws layout per batch: off[128] then aw[64].
// ---------------------------------------------------------------------------
__global__ __launch_bounds__(256) void precompute_kernel(
    const float* __restrict__ query,
    const float* __restrict__ W_off, const float* __restrict__ b_off,
    const float* __restrict__ W_attn, const float* __restrict__ b_attn,
    float* __restrict__ ws)
{
    const int b = blockIdx.x;
    const int t = threadIdx.x;
    __shared__ float sq[ED];
    __shared__ float red[256];
    __shared__ float sattn[64];

    sq[t] = query[b * ED + t];
    __syncthreads();

    // ---- offsets: col = t&127, k-half = t>>7 (128 k each) ----
    {
        const int col  = t & 127;
        const int half = t >> 7;
        const float* Wp = W_off + (size_t)half * 128 * 128 + col;
        const float* qp = sq + half * 128;
        float a0 = 0.f, a1 = 0.f, a2 = 0.f, a3 = 0.f;
        #pragma unroll 8
        for (int k = 0; k < 128; k += 4) {
            a0 = fmaf(qp[k + 0], Wp[(k + 0) * 128], a0);
            a1 = fmaf(qp[k + 1], Wp[(k + 1) * 128], a1);
            a2 = fmaf(qp[k + 2], Wp[(k + 2) * 128], a2);
            a3 = fmaf(qp[k + 3], Wp[(k + 3) * 128], a3);
        }
        red[t] = (a0 + a1) + (a2 + a3);
    }
    __syncthreads();
    if (t < 128) ws[b * 192 + t] = fmaxf(red[t] + red[t + 128] + b_off[t], 0.0f);
    __syncthreads();   // red reuse below

    // ---- attn: col = t&63, k-quarter = t>>6 (64 k each) ----
    {
        const int col = t & 63;
        const int qtr = t >> 6;
        const float* Wp = W_attn + (size_t)qtr * 64 * 64 + col;
        const float* qp = sq + qtr * 64;
        float a0 = 0.f, a1 = 0.f, a2 = 0.f, a3 = 0.f;
        #pragma unroll 8
        for (int k = 0; k < 64; k += 4) {
            a0 = fmaf(qp[k + 0], Wp[(k + 0) * 64], a0);
            a1 = fmaf(qp[k + 1], Wp[(k + 1) * 64], a1);
            a2 = fmaf(qp[k + 2], Wp[(k + 2) * 64], a2);
            a3 = fmaf(qp[k + 3], Wp[(k + 3) * 64], a3);
        }
        red[t] = (a0 + a1) + (a2 + a3);
    }
    __syncthreads();
    if (t < 64) {
        sattn[t] = fmaxf(red[t] + red[t + 64] + red[t + 128] + red[t + 192]
                         + b_attn[t], 0.0f);
    }
    __syncthreads();
    if (t < 64) {
        const int hh = t >> 3;
        float m = -1e30f;
        #pragma unroll
        for (int p = 0; p < NPTS; ++p) m = fmaxf(m, sattn[hh * NPTS + p]);
        float s = 0.0f;
        #pragma unroll
        for (int p = 0; p < NPTS; ++p) s += expf(sattn[hh * NPTS + p] - m);
        ws[b * 192 + 128 + t] = expf(sattn[t] - m) / s;
    }
}

// ---------------------------------------------------------------------------
// Kernel B v4.
//  - __launch_bounds__(256,4): permit up to 128 VGPR so 8 dwordx4 loads can
//    stay in flight (v3's plain bounds made the compiler target 8 waves/EU,
//    VGPR 36, and serialize the pipeline).
//  - s_idx/s_wt split arrays, lane-contiguous b128 writes (conflict-free;
//    v3's interleaved layout cost 3.67M conflict-cycles in phase-1 writes).
//    Lane l of phase-1 holds tuple (p = l>>3, h = l&7) so phase-2's read for
//    point p is 8 consecutive broadcast addresses (conflict-free).
//  - Phase 2: straight-line 2-point batches: 4 LDS b128 reads + 8 global
//    dwordx4 loads in one basic block, then 32 FMAs.
//  - blockIdx % bs pins batch b to XCD b: 4MB feat map resident in one L2.
// ---------------------------------------------------------------------------
__global__ __launch_bounds__(256, 4) void deform_attn_kernel(
    const float* __restrict__ feat,     // [bs, nq, NHEAD, DHEAD]
    const float* __restrict__ ref2d,    // [bs, nq, 1, 2]
    const float* __restrict__ query,    // [bs, 1, ED]
    const float* __restrict__ ln_g, const float* __restrict__ ln_b,
    const float* __restrict__ ws,       // [bs, 192]
    const int* __restrict__ Hp, const int* __restrict__ Wp,
    float* __restrict__ out,            // [bs, nq, ED]
    int nq, int bs)
{
    const int blk = blockIdx.x;
    const int b = blk % bs;                    // XCD swizzle
    const int qbase = (blk / bs) * QPB;
    const int t = threadIdx.x;

    __shared__ float s_off[128];
    __shared__ float s_aw[64];
    __shared__ float s_ref[QPB * 2];
    __shared__ int4   s_idx[QPB * 64];         // [q][lane]: lane = p*8+h
    __shared__ float4 s_wt [QPB * 64];

    if (t < 128)      s_off[t] = ws[b * 192 + t];
    else if (t < 192) s_aw[t - 128] = ws[b * 192 + t];
    else if (t < 192 + QPB * 2) {
        const int i = t - 192;                 // i = qL*2 + j
        s_ref[i] = ref2d[(b * nq + qbase + (i >> 1)) * 2 + (i & 1)];
    }
    const int H = Hp[0];
    const int W = Wp[0];
    __syncthreads();

    // ---- Phase 1: 8*64 tuples, 2 per thread; lane l -> (p=l>>3, h=l&7) ----
    #pragma unroll
    for (int u = t; u < QPB * 64; u += 256) {
        const int qL = u >> 6;
        const int l  = u & 63;
        const int p  = l >> 3;
        const int h  = l & 7;
        const int hp = h * 8 + p;

        const float x = s_ref[qL * 2 + 0] * (float)W - 0.5f + s_off[hp * 2 + 0];
        const float y = s_ref[qL * 2 + 1] * (float)H - 0.5f + s_off[hp * 2 + 1];
        const float aw = s_aw[hp];

        const float xf = floorf(x);
        const float yf = floorf(y);
        const int ix = (int)xf;
        const int iy = (int)yf;
        const float wx = x - xf;
        const float wy = y - yf;

        const bool vx0 = (ix >= 0) && (ix < W);
        const bool vx1 = (ix + 1 >= 0) && (ix + 1 < W);
        const bool vy0 = (iy >= 0) && (iy < H);
        const bool vy1 = (iy + 1 >= 0) && (iy + 1 < H);
        const int cx0 = min(max(ix, 0), W - 1);
        const int cx1 = min(max(ix + 1, 0), W - 1);
        const int cy0 = min(max(iy, 0), H - 1);
        const int cy1 = min(max(iy + 1, 0), H - 1);

        const int r0 = cy0 * W;
        const int r1 = cy1 * W;
        int4 idx;
        idx.x = r0 + cx0;
        idx.y = r0 + cx1;
        idx.z = r1 + cx0;
        idx.w = r1 + cx1;

        const float awx = aw * wx, awix = aw - awx;     // aw*(1-wx)
        float4 wt;
        wt.x = (vx0 && vy0) ? awix * (1.0f - wy) : 0.0f;
        wt.y = (vx1 && vy0) ? awx  * (1.0f - wy) : 0.0f;
        wt.z = (vx0 && vy1) ? awix * wy          : 0.0f;
        wt.w = (vx1 && vy1) ? awx  * wy          : 0.0f;

        s_idx[u] = idx;                        // lane-contiguous b128 writes
        s_wt[u]  = wt;
    }
    __syncthreads();

    // ---- Phase 2: gather, 2-point straight-line batches ----
    const int qL   = t >> 6;
    const int lane = t & 63;
    const int h    = lane >> 3;
    const int c4   = lane & 7;

    const float* fb = feat + (size_t)b * nq * ED + h * DHEAD + c4 * 4;
    const float4 qv = *(const float4*)(query + b * ED + lane * 4);
    const float4 g  = *(const float4*)(ln_g + lane * 4);
    const float4 be = *(const float4*)(ln_b + lane * 4);

    #pragma unroll
    for (int gq = 0; gq < QPB / 4; ++gq) {
        const int qloc = gq * 4 + qL;
        const int q = qbase + qloc;
        const int cb = qloc * 64 + h;          // + p*8 per point

        float ax = 0.f, ay = 0.f, az = 0.f, aw4 = 0.f;

        #pragma unroll
        for (int pp = 0; pp < NPTS; pp += 2) {
            const int4   iA = s_idx[cb + pp * 8];
            const float4 wA = s_wt [cb + pp * 8];
            const int4   iB = s_idx[cb + pp * 8 + 8];
            const float4 wB = s_wt [cb + pp * 8 + 8];

            const float4 a0 = *(const float4*)(fb + (size_t)iA.x * ED);
            const float4 a1 = *(const float4*)(fb + (size_t)iA.y * ED);
            const float4 a2 = *(const float4*)(fb + (size_t)iA.z * ED);
            const float4 a3 = *(const float4*)(fb + (size_t)iA.w * ED);
            const float4 b0 = *(const float4*)(fb + (size_t)iB.x * ED);
            const float4 b1 = *(const float4*)(fb + (size_t)iB.y * ED);
            const float4 b2 = *(const float4*)(fb + (size_t)iB.z * ED);
            const float4 b3 = *(const float4*)(fb + (size_t)iB.w * ED);

            ax = fmaf(wA.x, a0.x, ax); ay = fmaf(wA.x, a0.y, ay);
            az = fmaf(wA.x, a0.z, az); aw4 = fmaf(wA.x, a0.w, aw4);
            ax = fmaf(wA.y, a1.x, ax); ay = fmaf(wA.y, a1.y, ay);
            az = fmaf(wA.y, a1.z, az); aw4 = fmaf(wA.y, a1.w, aw4);
            ax = fmaf(wA.z, a2.x, ax); ay = fmaf(wA.z, a2.y, ay);
            az = fmaf(wA.z, a2.z, az); aw4 = fmaf(wA.z, a2.w, aw4);
            ax = fmaf(wA.w, a3.x, ax); ay = fmaf(wA.w, a3.y, ay);
            az = fmaf(wA.w, a3.z, az); aw4 = fmaf(wA.w, a3.w, aw4);

            ax = fmaf(wB.x, b0.x, ax); ay = fmaf(wB.x, b0.y, ay);
            az = fmaf(wB.x, b0.z, az); aw4 = fmaf(wB.x, b0.w, aw4);
            ax = fmaf(wB.y, b1.x, ax); ay = fmaf(wB.y, b1.y, ay);
            az = fmaf(wB.y, b1.z, az); aw4 = fmaf(wB.y, b1.w, aw4);
            ax = fmaf(wB.z, b2.x, ax); ay = fmaf(wB.z, b2.y, ay);
            az = fmaf(wB.z, b2.z, az); aw4 = fmaf(wB.z, b2.w, aw4);
            ax = fmaf(wB.w, b3.x, ax); ay = fmaf(wB.w, b3.y, ay);
            az = fmaf(wB.w, b3.z, az); aw4 = fmaf(wB.w, b3.w, aw4);
        }

        // ---- Phase 3: residual + wave-local LayerNorm ----
        const float r0 = ax + qv.x;
        const float r1 = ay + qv.y;
        const float r2 = az + qv.z;
        const float r3 = aw4 + qv.w;

        float s  = (r0 + r1) + (r2 + r3);
        float ss = fmaf(r0, r0, fmaf(r1, r1, fmaf(r2, r2, r3 * r3)));
        #pragma unroll
        for (int m = 1; m < 64; m <<= 1) {
            s  += __shfl_xor(s, m, 64);
            ss += __shfl_xor(ss, m, 64);
        }
        const float mean = s * (1.0f / ED);
        const float var  = ss * (1.0f / ED) - mean * mean;
        const float inv  = rsqrtf(var + 1e-5f);

        float4 o;
        o.x = (r0 - mean) * inv * g.x + be.x;
        o.y = (r1 - mean) * inv * g.y + be.y;
        o.z = (r2 - mean) * inv * g.z + be.z;
        o.w = (r3 - mean) * inv * g.w + be.w;
        *(float4*)(out + ((size_t)b * nq + q) * ED + lane * 4) = o;
    }
}

extern "C" void kernel_launch(void* const* d_in, const int* in_sizes, int n_in,
                              void* d_out, int out_size, void* d_ws, size_t ws_size,
                              hipStream_t stream)
{
    const float* query  = (const float*)d_in[0];
    const float* feat   = (const float*)d_in[1];
    const float* ref2d  = (const float*)d_in[2];
    const float* W_off  = (const float*)d_in[3];
    const float* b_off  = (const float*)d_in[4];
    const float* W_attn = (const float*)d_in[5];
    const float* b_attn = (const float*)d_in[6];
    const float* ln_g   = (const float*)d_in[7];
    const float* ln_b   = (const float*)d_in[8];
    const int*   Hp     = (const int*)d_in[9];
    const int*   Wp     = (const int*)d_in[10];
    float* out = (float*)d_out;
    float* ws  = (float*)d_ws;

    const int bs = in_sizes[0] / ED;            // 8
    const int nq = in_sizes[2] / (bs * 2);      // h*w = 4096

    precompute_kernel<<<bs, 256, 0, stream>>>(query, W_off, b_off, W_attn, b_attn, ws);
    deform_attn_kernel<<<bs * nq / QPB, 256, 0, stream>>>(feat, ref2d, query, ln_g, ln_b,
                                                          ws, Hp, Wp, out, nq, bs);
}